// Round 19
// baseline (261.876 us; speedup 1.0000x reference)
//
#include <hip/hip_runtime.h>
#include <stdint.h>

#define QLEN 1024
#define KLEN 2048
#define BSZ  4
#define NH   16
#define HD   64
#define EMB  1024
#define PREVL 1024
#define SLOG2E 0.045084220027780106f   // (1/32) * log2(e): fold softmax scale + exp2 conversion

typedef __attribute__((ext_vector_type(4))) float f32x4;
typedef __attribute__((ext_vector_type(8))) short bf16x8;

__device__ __forceinline__ unsigned short f2bf(float f){
  unsigned u = __float_as_uint(f);
  u += 0x7fffu + ((u >> 16) & 1u);
  return (unsigned short)(u >> 16);
}

__device__ __forceinline__ void gload_lds16(const void* g, void* l){
  __builtin_amdgcn_global_load_lds((const __attribute__((address_space(1))) void*)g,
                                   (__attribute__((address_space(3))) void*)l, 16, 0, 0);
}

// ---------------- fused prep: 5x W transpose (f32 [k][n] -> bf16 [n][k]) + q/k/v/p cvt ----------------
__global__ void txl_prep(const float* __restrict__ w0, const float* __restrict__ w1,
                         const float* __restrict__ w2, const float* __restrict__ w3,
                         const float* __restrict__ w4,
                         unsigned short* __restrict__ o0, unsigned short* __restrict__ o1,
                         unsigned short* __restrict__ o2, unsigned short* __restrict__ o3,
                         unsigned short* __restrict__ o4,
                         const float* __restrict__ q, const float* __restrict__ k,
                         const float* __restrict__ v, const float* __restrict__ p,
                         unsigned short* __restrict__ qo, unsigned short* __restrict__ ko,
                         unsigned short* __restrict__ vo, unsigned short* __restrict__ po){
  const int bid = blockIdx.x;
  if (bid < 5120){
    const int z = bid >> 10, rem = bid & 1023;
    const int by = rem >> 5, bx = rem & 31;
    const float* in; unsigned short* out;
    switch (z){
      case 0: in = w0; out = o0; break;
      case 1: in = w1; out = o1; break;
      case 2: in = w2; out = o2; break;
      case 3: in = w3; out = o3; break;
      default: in = w4; out = o4; break;
    }
    __shared__ float tile[32][33];
    int tx = threadIdx.x & 31, ty = threadIdx.x >> 5;
    int k0 = by * 32, n0 = bx * 32;
    #pragma unroll
    for (int j = 0; j < 32; j += 8)
      tile[ty + j][tx] = in[(size_t)(k0 + ty + j) * EMB + n0 + tx];
    __syncthreads();
    #pragma unroll
    for (int j = 0; j < 32; j += 8)
      out[(size_t)(n0 + ty + j) * EMB + k0 + tx] = f2bf(tile[tx][ty + j]);
  } else {
    for (size_t c = (size_t)(bid - 5120) * 256 + threadIdx.x; c < 2883584; c += (size_t)2048 * 256){
      const float* src; unsigned short* dst; size_t off;
      if (c < 524288)      { src = q; dst = qo; off = c; }
      else if (c < 1572864){ src = k; dst = ko; off = c - 524288; }
      else if (c < 2621440){ src = v; dst = vo; off = c - 1572864; }
      else                 { src = p; dst = po; off = c - 2621440; }
      f32x4 a = *(const f32x4*)(src + off * 8);
      f32x4 b = *(const f32x4*)(src + off * 8 + 4);
      bf16x8 r;
      #pragma unroll
      for (int u = 0; u < 4; ++u){ r[u] = (short)f2bf(a[u]); r[u + 4] = (short)f2bf(b[u]); }
      *(bf16x8*)(dst + off * 8) = r;
    }
  }
}

// ---------------- fused projection GEMMs: R | Q(dual) | K | V in ONE launch ----------------
// XCD swizzle: wg = (bid%8)*176 + bid/8 -> each XCD owns contiguous m-panels + shared Wt.
// Mode 2 (V) uses an LDS-transpose epilogue: acc -> scratch[d][b][kp] -> coalesced 16B stores.
__global__ __launch_bounds__(256)
void txl_gemm_proj(const unsigned short* __restrict__ pbf, const unsigned short* __restrict__ qbf,
                   const unsigned short* __restrict__ kbf, const unsigned short* __restrict__ vbf,
                   const unsigned short* __restrict__ WpT, const unsigned short* __restrict__ WqT,
                   const unsigned short* __restrict__ WkT, const unsigned short* __restrict__ WvT,
                   const float* __restrict__ bq, const float* __restrict__ bk,
                   const float* __restrict__ bv, const float* __restrict__ U,
                   const float* __restrict__ V,
                   unsigned short* __restrict__ Rb, unsigned short* __restrict__ Qu,
                   unsigned short* __restrict__ Qv, unsigned short* __restrict__ Kb,
                   unsigned short* __restrict__ Vt){
  const int bid = (blockIdx.x & 7) * 176 + (blockIdx.x >> 3);   // XCD-contiguous work ids
  int mode, local;
  const unsigned short *Ag, *Wt;
  if (bid < 128)      { mode = 3; local = bid;       Ag = pbf; Wt = WpT; }
  else if (bid < 384) { mode = 0; local = bid - 128; Ag = qbf; Wt = WqT; }
  else if (bid < 896) { mode = 1; local = bid - 384; Ag = kbf; Wt = WkT; }
  else                { mode = 2; local = bid - 896; Ag = vbf; Wt = WvT; }
  const int m0 = (local >> 3) * 128, n0 = (local & 7) * 128;

  const int tid = threadIdx.x;
  const int lane = tid & 63, wave = tid >> 6;
  const int lr = lane & 15, lg = lane >> 4;
  const int wm = wave >> 1, wn = wave & 1;
  __shared__ union {
    struct { unsigned short At[128 * 64]; unsigned short Bt[128 * 64]; } ab;  // 32 KB
    unsigned short tr[64 * 136];                                              // 17 KB scratch
  } smem;
  unsigned short* At = smem.ab.At;
  unsigned short* Bt = smem.ab.Bt;
  f32x4 acc[4][4] = {};

  for (int kt = 0; kt < EMB / 64; ++kt){
    const int k0 = kt * 64;
    __syncthreads();
    #pragma unroll
    for (int j = 0; j < 4; ++j){
      int row = j * 32 + (tid >> 3);
      int g = (tid & 7) ^ (row & 7);
      gload_lds16(Ag + (size_t)(m0 + row) * EMB + k0 + g * 8, &At[j * 2048 + wave * 512]);
      gload_lds16(Wt + (size_t)(n0 + row) * EMB + k0 + g * 8, &Bt[j * 2048 + wave * 512]);
    }
    __syncthreads();
    #pragma unroll
    for (int ks = 0; ks < 2; ++ks){
      bf16x8 af[4], bfr[4];
      #pragma unroll
      for (int mb = 0; mb < 4; ++mb){
        int row = wm * 64 + mb * 16 + lr;
        af[mb] = *(const bf16x8*)&At[row * 64 + ((lg + 4 * ks) ^ (row & 7)) * 8];
      }
      #pragma unroll
      for (int nb = 0; nb < 4; ++nb){
        int row = wn * 64 + nb * 16 + lr;
        bfr[nb] = *(const bf16x8*)&Bt[row * 64 + ((lg + 4 * ks) ^ (row & 7)) * 8];
      }
      __builtin_amdgcn_s_setprio(1);
      #pragma unroll
      for (int mb = 0; mb < 4; ++mb)
        #pragma unroll
        for (int nb = 0; nb < 4; ++nb)
          acc[mb][nb] = __builtin_amdgcn_mfma_f32_16x16x32_bf16(af[mb], bfr[nb], acc[mb][nb], 0, 0, 0);
      __builtin_amdgcn_s_setprio(0);
    }
  }

  if (mode == 2){
    // ---- LDS-transpose epilogue for coalesced Vt[b][h][d][kp] stores ----
    const int kp0 = m0 >> 2;
    __syncthreads();                       // At/Bt dead: all fragment reads complete
    #pragma unroll
    for (int pass = 0; pass < 2; ++pass){
      if (wn == pass){
        #pragma unroll
        for (int mb = 0; mb < 4; ++mb){
          int kp_l = wm * 16 + mb * 4 + lg;
          #pragma unroll
          for (int nb = 0; nb < 4; ++nb){
            int nl = nb * 16 + lr;         // 0..63 within this half
            float bvv = bv[n0 + pass * 64 + nl];
            #pragma unroll
            for (int i = 0; i < 4; ++i)
              smem.tr[nl * 136 + i * 32 + kp_l] = f2bf(acc[mb][nb][i] + bvv);
          }
        }
      }
      __syncthreads();
      #pragma unroll
      for (int it = 0; it < 4; ++it){
        int c = it * 256 + tid;
        int nl = c >> 4, bb = (c >> 2) & 3, kpc = c & 3;
        int n = n0 + pass * 64 + nl;
        int hh = n >> 6, dd = n & 63;
        bf16x8 vv = *(const bf16x8*)&smem.tr[nl * 136 + bb * 32 + kpc * 8];
        *(bf16x8*)&Vt[((((size_t)bb * NH + hh) * HD) + dd) * KLEN + kp0 + kpc * 8] = vv;
      }
      __syncthreads();
    }
  } else {
    #pragma unroll
    for (int mb = 0; mb < 4; ++mb){
      #pragma unroll
      for (int nb = 0; nb < 4; ++nb){
        #pragma unroll
        for (int i = 0; i < 4; ++i){
          int m = m0 + wm * 64 + mb * 16 + 4 * lg + i;
          int n = n0 + wn * 64 + nb * 16 + lr;
          float v = acc[mb][nb][i];
          if (mode == 0){
            int qq = m >> 2, b = m & 3, h = n >> 6, d = n & 63;
            size_t idx = ((((size_t)b * NH + h) * QLEN) + qq) * HD + d;
            float base = v + bq[n];
            Qu[idx] = f2bf((base + U[n]) * SLOG2E);
            Qv[idx] = f2bf((base + V[n]) * SLOG2E);
          } else if (mode == 1){
            int kp = m >> 2, b = m & 3, h = n >> 6, d = n & 63;
            Kb[((((size_t)b * NH + h) * KLEN) + kp) * HD + d] = f2bf(v + bk[n]);
          } else {
            int h = n >> 6, d = n & 63;
            Rb[((size_t)h * KLEN + m) * HD + d] = f2bf(v);
          }
        }
      }
    }
  }
}

// ---------------- output GEMM: d_out[M][1024] = alpha @ WoT^T + bo (f32 out) ----------------
// 1-D grid of 256, XCD swizzle: each XCD owns 4 contiguous m-panels + shared WoT.
__global__ __launch_bounds__(256)
void txl_gemm_out(const unsigned short* __restrict__ Ag, const unsigned short* __restrict__ Wt,
                  const float* __restrict__ bias, float* __restrict__ out0){
  const int wg = (blockIdx.x & 7) * 32 + (blockIdx.x >> 3);
  const int m0 = (wg >> 3) * 128, n0 = (wg & 7) * 128;
  const int tid = threadIdx.x;
  const int lane = tid & 63, wave = tid >> 6;
  const int lr = lane & 15, lg = lane >> 4;
  const int wm = wave >> 1, wn = wave & 1;
  __shared__ unsigned short At[128 * 64];
  __shared__ unsigned short Bt[128 * 64];
  f32x4 acc[4][4] = {};

  for (int kt = 0; kt < EMB / 64; ++kt){
    const int k0 = kt * 64;
    __syncthreads();
    #pragma unroll
    for (int j = 0; j < 4; ++j){
      int row = j * 32 + (tid >> 3);
      int g = (tid & 7) ^ (row & 7);
      gload_lds16(Ag + (size_t)(m0 + row) * EMB + k0 + g * 8, &At[j * 2048 + wave * 512]);
      gload_lds16(Wt + (size_t)(n0 + row) * EMB + k0 + g * 8, &Bt[j * 2048 + wave * 512]);
    }
    __syncthreads();
    #pragma unroll
    for (int ks = 0; ks < 2; ++ks){
      bf16x8 af[4], bfr[4];
      #pragma unroll
      for (int mb = 0; mb < 4; ++mb){
        int row = wm * 64 + mb * 16 + lr;
        af[mb] = *(const bf16x8*)&At[row * 64 + ((lg + 4 * ks) ^ (row & 7)) * 8];
      }
      #pragma unroll
      for (int nb = 0; nb < 4; ++nb){
        int row = wn * 64 + nb * 16 + lr;
        bfr[nb] = *(const bf16x8*)&Bt[row * 64 + ((lg + 4 * ks) ^ (row & 7)) * 8];
      }
      __builtin_amdgcn_s_setprio(1);
      #pragma unroll
      for (int mb = 0; mb < 4; ++mb)
        #pragma unroll
        for (int nb = 0; nb < 4; ++nb)
          acc[mb][nb] = __builtin_amdgcn_mfma_f32_16x16x32_bf16(af[mb], bfr[nb], acc[mb][nb], 0, 0, 0);
      __builtin_amdgcn_s_setprio(0);
    }
  }
  #pragma unroll
  for (int mb = 0; mb < 4; ++mb)
    #pragma unroll
    for (int nb = 0; nb < 4; ++nb)
      #pragma unroll
      for (int i = 0; i < 4; ++i){
        int m = m0 + wm * 64 + mb * 16 + 4 * lg + i;
        int n = n0 + wn * 64 + nb * 16 + lr;
        out0[(size_t)m * EMB + n] = acc[mb][nb][i] + bias[n];
      }
}

// ---------------- fused attention: R18 (best): ring + mask-peel + XCD swizzle ----------------
__global__ __launch_bounds__(256)
void txl_attn(const unsigned short* __restrict__ Qu, const unsigned short* __restrict__ Qv,
              const unsigned short* __restrict__ Kb, const unsigned short* __restrict__ Vt,
              const unsigned short* __restrict__ Rb, unsigned short* __restrict__ alpha){
  const int tid = threadIdx.x, lane = tid & 63, wave = tid >> 6;
  const int lr = lane & 15, lg = lane >> 4;
  const int wg = (blockIdx.x & 7) * 128 + (blockIdx.x >> 3);   // XCD-contiguous (h,b) groups
  const int qt = 15 - (wg & 15);               // longest blocks first within each group
  const int hb = wg >> 4;
  const int h = hb & 15, b = hb >> 4;
  const int q0 = qt * 64;
  const int myq0 = q0 + 16 * wave;

  __shared__ union { unsigned short q[2][64 * 64]; unsigned short p[4][16 * 64]; } smq; // 16 KB
  __shared__ unsigned short sm_k[64 * 64];      // 8 KB
  __shared__ unsigned short sm_v[64 * 64];      // 8 KB
  __shared__ unsigned short sm_r[128 * 64];     // 16 KB ring
  __shared__ float sm_t[4][16 * 81];            // 20.25 KB

  const unsigned short* quB = Qu + (((size_t)b * NH + h) * QLEN) * HD;
  const unsigned short* qvB = Qv + (((size_t)b * NH + h) * QLEN) * HD;
  const unsigned short* kB  = Kb + (((size_t)b * NH + h) * KLEN) * HD;
  const unsigned short* vB  = Vt + (((size_t)b * NH + h) * HD) * KLEN;
  const unsigned short* rB  = Rb + ((size_t)h * KLEN) * HD;

  // stage Qu/Qv tiles + full first R band [rbase0, rbase0+128)
  #pragma unroll
  for (int j = 0; j < 2; ++j){
    int row = j * 32 + (tid >> 3);
    int g = (tid & 7) ^ (row & 7);
    gload_lds16(quB + (size_t)(q0 + row) * HD + g * 8, &smq.q[0][j * 2048 + wave * 512]);
    gload_lds16(qvB + (size_t)(q0 + row) * HD + g * 8, &smq.q[1][j * 2048 + wave * 512]);
  }
  const int rbase0 = (QLEN - 64) - q0;         // kt=0 band origin (multiple of 64, <= 960)
  #pragma unroll
  for (int j = 0; j < 4; ++j){
    int S = rbase0 + j * 32;                   // block start; S&7 == 0
    int rs = S + (tid >> 3);                   // < 1088, no clamp needed
    int g = (tid & 7) ^ (rs & 7);
    gload_lds16(rB + (size_t)rs * HD + g * 8, &sm_r[(S & 127) * 64 + wave * 512]);
  }
  __syncthreads();
  bf16x8 qfu[2], qfv[2];
  {
    int row = 16 * wave + lr;
    #pragma unroll
    for (int ks = 0; ks < 2; ++ks){
      qfu[ks] = *(const bf16x8*)&smq.q[0][row * 64 + ((lg + 4 * ks) ^ (row & 7)) * 8];
      qfv[ks] = *(const bf16x8*)&smq.q[1][row * 64 + ((lg + 4 * ks) ^ (row & 7)) * 8];
    }
  }

  f32x4 o[4] = {};
  float ls[4] = {0.f, 0.f, 0.f, 0.f};

  const int nk = qt + 17;                      // qt <= 15 -> nk <= 32 always
  const int roff = 48 - 16 * wave;             // this wave's R rows within the 128-row band

  for (int kt = 0; kt < nk; ++kt){
    const int k0 = kt * 64;
    const int rbase = k0 + (QLEN - 64) - q0;   // band origin (>= 0, multiple of 64)
    const int roff64 = rbase & 64;             // ring rotation for this tile
    __syncthreads();
    // stage K, V tiles
    #pragma unroll
    for (int j = 0; j < 2; ++j){
      int row = j * 32 + (tid >> 3);
      int g = (tid & 7) ^ (row & 7);
      gload_lds16(kB + (size_t)(k0 + row) * HD + g * 8, &sm_k[j * 2048 + wave * 512]);
      gload_lds16(vB + (size_t)row * KLEN + k0 + g * 8, &sm_v[j * 2048 + wave * 512]);
    }
    // ring: stage only the 64 NEW band rows [rbase+64, rbase+128) (kt>0);
    // their slots held rows expired two tiles ago — loop-top barrier protects them.
    if (kt > 0){
      #pragma unroll
      for (int j = 0; j < 2; ++j){
        int S = rbase + 64 + j * 32;           // block start; S&7 == 0
        int rs = S + (tid >> 3);
        int rc = rs < KLEN - 1 ? rs : KLEN - 1;
        int g = (tid & 7) ^ (rs & 7);
        gload_lds16(rB + (size_t)rc * HD + g * 8, &sm_r[(S & 127) * 64 + wave * 512]);
      }
    }
    __syncthreads();

    // content scores S_c[16q][64k] and position band T[16q][80r]
    f32x4 sc[4] = {};
    f32x4 tt[5] = {};
    __builtin_amdgcn_s_setprio(1);
    #pragma unroll
    for (int ks = 0; ks < 2; ++ks){
      #pragma unroll
      for (int nb = 0; nb < 4; ++nb){
        int row = nb * 16 + lr;
        bf16x8 kf = *(const bf16x8*)&sm_k[row * 64 + ((lg + 4 * ks) ^ (row & 7)) * 8];
        sc[nb] = __builtin_amdgcn_mfma_f32_16x16x32_bf16(qfu[ks], kf, sc[nb], 0, 0, 0);
      }
      #pragma unroll
      for (int rb = 0; rb < 5; ++rb){
        int row = roff + rb * 16 + lr;
        int slot = row ^ roff64;               // ring-rotated slot; slot&7 == row&7
        bf16x8 rf = *(const bf16x8*)&sm_r[slot * 64 + ((lg + 4 * ks) ^ (row & 7)) * 8];
        tt[rb] = __builtin_amdgcn_mfma_f32_16x16x32_bf16(qfv[ks], rf, tt[rb], 0, 0, 0);
      }
    }
    __builtin_amdgcn_s_setprio(0);

    // sm_t round-trip for the rel-shift diagonal (per-wave region; stride 81)
    float* tw = sm_t[wave];
    #pragma unroll
    for (int rb = 0; rb < 5; ++rb)
      #pragma unroll
      for (int i = 0; i < 4; ++i)
        tw[(4 * lg + i) * 81 + rb * 16 + lr] = tt[rb][i];
    asm volatile("s_waitcnt lgkmcnt(0)" ::: "memory");

    // assemble scores, exp2 (fixed-max), deferred row-sum, write P.
    // Mask applies ONLY in the final tile (k0+63 > q0+1024 iff kt == nk-1).
    if (kt + 1 < nk){
      #pragma unroll
      for (int i = 0; i < 4; ++i){
        int qq = 4 * lg + i;
        float rs = 0.f;
        #pragma unroll
        for (int nb = 0; nb < 4; ++nb){
          int kk = nb * 16 + lr;
          float p = exp2f(sc[nb][i] + tw[qq * 81 + kk + 15 - qq]);
          rs += p;
          smq.p[wave][qq * 64 + (((kk >> 3) ^ (qq & 7)) << 3) + (kk & 7)] = f2bf(p);
        }
        ls[i] += rs;
      }
    } else {
      #pragma unroll
      for (int i = 0; i < 4; ++i){
        int qq = 4 * lg + i;
        int qglob = myq0 + qq;
        float rs = 0.f;
        #pragma unroll
        for (int nb = 0; nb < 4; ++nb){
          int kk = nb * 16 + lr;
          float s = sc[nb][i] + tw[qq * 81 + kk + 15 - qq];
          if (k0 + kk > qglob + PREVL) s = -1e30f;
          float p = exp2f(s);
          rs += p;
          smq.p[wave][qq * 64 + (((kk >> 3) ^ (qq & 7)) << 3) + (kk & 7)] = f2bf(p);
        }
        ls[i] += rs;
      }
    }
    asm volatile("s_waitcnt lgkmcnt(0)" ::: "memory");

    // PV: O[16q][64d] += P @ V
    __builtin_amdgcn_s_setprio(1);
    #pragma unroll
    for (int ks = 0; ks < 2; ++ks){
      bf16x8 pa = *(const bf16x8*)&smq.p[wave][lr * 64 + ((lg + 4 * ks) ^ (lr & 7)) * 8];
      #pragma unroll
      for (int db = 0; db < 4; ++db){
        int row = db * 16 + lr;
        bf16x8 vf = *(const bf16x8*)&sm_v[row * 64 + ((lg + 4 * ks) ^ (row & 7)) * 8];
        o[db] = __builtin_amdgcn_mfma_f32_16x16x32_bf16(pa, vf, o[db], 0, 0, 0);
      }
    }
    __builtin_amdgcn_s_setprio(0);
  }

  // epilogue: reduce deferred row-sums, normalize, write alpha[q][b][h*64+d]
  #pragma unroll
  for (int i = 0; i < 4; ++i){
    float s = ls[i];
    s += __shfl_xor(s, 1); s += __shfl_xor(s, 2);
    s += __shfl_xor(s, 4); s += __shfl_xor(s, 8);
    float inv = 1.0f / s;
    int q = myq0 + 4 * lg + i;
    #pragma unroll
    for (int db = 0; db < 4; ++db){
      int e = (h << 6) + db * 16 + lr;
      alpha[((size_t)q * BSZ + b) * EMB + e] = f2bf(o[db][i] * inv);
    }
  }
}

extern "C" void kernel_launch(void* const* d_in, const int* in_sizes, int n_in,
                              void* d_out, int out_size, void* d_ws, size_t ws_size,
                              hipStream_t stream) {
  const float* query = (const float*)d_in[0];
  const float* key   = (const float*)d_in[1];
  const float* value = (const float*)d_in[2];
  const float* pos   = (const float*)d_in[3];
  const float* U     = (const float*)d_in[4];
  const float* V     = (const float*)d_in[5];
  const float* Wq    = (const float*)d_in[6];
  const float* bq    = (const float*)d_in[7];
  const float* Wk    = (const float*)d_in[8];
  const float* bk    = (const float*)d_in[9];
  const float* Wv    = (const float*)d_in[10];
  const float* bv    = (const float*)d_in[11];
  const float* Wp    = (const float*)d_in[12];
  const float* Wo    = (const float*)d_in[13];
  const float* bo    = (const float*)d_in[14];

  char* w = (char*)d_ws;
  const size_t MB = 1u << 20;
  unsigned short* WqT = (unsigned short*)(w + 0 * MB);
  unsigned short* WkT = (unsigned short*)(w + 2 * MB);
  unsigned short* WvT = (unsigned short*)(w + 4 * MB);
  unsigned short* WpT = (unsigned short*)(w + 6 * MB);
  unsigned short* WoT = (unsigned short*)(w + 8 * MB);
  unsigned short* Qu  = (unsigned short*)(w + 10 * MB);
  unsigned short* Qv  = (unsigned short*)(w + 18 * MB);
  unsigned short* Kb  = (unsigned short*)(w + 26 * MB);
  unsigned short* Vt  = (unsigned short*)(w + 42 * MB);
  unsigned short* Rb  = (unsigned short*)(w + 58 * MB);
  unsigned short* qbf = (unsigned short*)(w + 62 * MB);   // dead after proj-GEMM -> alpha
  unsigned short* kbf = (unsigned short*)(w + 70 * MB);
  unsigned short* vbf = (unsigned short*)(w + 86 * MB);
  unsigned short* pbf = (unsigned short*)(w + 102 * MB);
  unsigned short* alpha = qbf;

  txl_prep<<<dim3(7168), 256, 0, stream>>>(Wq, Wk, Wv, Wp, Wo, WqT, WkT, WvT, WpT, WoT,
                                           query, key, value, pos, qbf, kbf, vbf, pbf);

  txl_gemm_proj<<<dim3(1408), 256, 0, stream>>>(pbf, qbf, kbf, vbf, WpT, WqT, WkT, WvT,
                                                bq, bk, bv, U, V, Rb, Qu, Qv, Kb, Vt);

  txl_attn<<<dim3(1024), 256, 0, stream>>>(Qu, Qv, Kb, Vt, Rb, alpha);

  txl_gemm_out<<<dim3(256), 256, 0, stream>>>(alpha, WoT, bo, (float*)d_out);
}

// Round 20
// 256.099 us; speedup vs baseline: 1.0226x; 1.0226x over previous
//
#include <hip/hip_runtime.h>
#include <stdint.h>

#define QLEN 1024
#define KLEN 2048
#define BSZ  4
#define NH   16
#define HD   64
#define EMB  1024
#define PREVL 1024
#define SLOG2E 0.045084220027780106f   // (1/32) * log2(e): fold softmax scale + exp2 conversion

typedef __attribute__((ext_vector_type(4))) float f32x4;
typedef __attribute__((ext_vector_type(8))) short bf16x8;

__device__ __forceinline__ unsigned short f2bf(float f){
  unsigned u = __float_as_uint(f);
  u += 0x7fffu + ((u >> 16) & 1u);
  return (unsigned short)(u >> 16);
}

__device__ __forceinline__ void gload_lds16(const void* g, void* l){
  __builtin_amdgcn_global_load_lds((const __attribute__((address_space(1))) void*)g,
                                   (__attribute__((address_space(3))) void*)l, 16, 0, 0);
}

// ---------------- fused prep: 5x W transpose (f32 [k][n] -> bf16 [n][k]) + q/k/v/p cvt ----------------
__global__ void txl_prep(const float* __restrict__ w0, const float* __restrict__ w1,
                         const float* __restrict__ w2, const float* __restrict__ w3,
                         const float* __restrict__ w4,
                         unsigned short* __restrict__ o0, unsigned short* __restrict__ o1,
                         unsigned short* __restrict__ o2, unsigned short* __restrict__ o3,
                         unsigned short* __restrict__ o4,
                         const float* __restrict__ q, const float* __restrict__ k,
                         const float* __restrict__ v, const float* __restrict__ p,
                         unsigned short* __restrict__ qo, unsigned short* __restrict__ ko,
                         unsigned short* __restrict__ vo, unsigned short* __restrict__ po){
  const int bid = blockIdx.x;
  if (bid < 5120){
    const int z = bid >> 10, rem = bid & 1023;
    const int by = rem >> 5, bx = rem & 31;
    const float* in; unsigned short* out;
    switch (z){
      case 0: in = w0; out = o0; break;
      case 1: in = w1; out = o1; break;
      case 2: in = w2; out = o2; break;
      case 3: in = w3; out = o3; break;
      default: in = w4; out = o4; break;
    }
    __shared__ float tile[32][33];
    int tx = threadIdx.x & 31, ty = threadIdx.x >> 5;
    int k0 = by * 32, n0 = bx * 32;
    #pragma unroll
    for (int j = 0; j < 32; j += 8)
      tile[ty + j][tx] = in[(size_t)(k0 + ty + j) * EMB + n0 + tx];
    __syncthreads();
    #pragma unroll
    for (int j = 0; j < 32; j += 8)
      out[(size_t)(n0 + ty + j) * EMB + k0 + tx] = f2bf(tile[tx][ty + j]);
  } else {
    for (size_t c = (size_t)(bid - 5120) * 256 + threadIdx.x; c < 2883584; c += (size_t)2048 * 256){
      const float* src; unsigned short* dst; size_t off;
      if (c < 524288)      { src = q; dst = qo; off = c; }
      else if (c < 1572864){ src = k; dst = ko; off = c - 524288; }
      else if (c < 2621440){ src = v; dst = vo; off = c - 1572864; }
      else                 { src = p; dst = po; off = c - 2621440; }
      f32x4 a = *(const f32x4*)(src + off * 8);
      f32x4 b = *(const f32x4*)(src + off * 8 + 4);
      bf16x8 r;
      #pragma unroll
      for (int u = 0; u < 4; ++u){ r[u] = (short)f2bf(a[u]); r[u + 4] = (short)f2bf(b[u]); }
      *(bf16x8*)(dst + off * 8) = r;
    }
  }
}

// ---------------- fused projection GEMMs: R | Q(dual) | K | V in ONE launch ----------------
// Mode 2 (V) uses an LDS-transpose epilogue: acc -> scratch[d][b][kp] -> coalesced 16B stores.
__global__ __launch_bounds__(256)
void txl_gemm_proj(const unsigned short* __restrict__ pbf, const unsigned short* __restrict__ qbf,
                   const unsigned short* __restrict__ kbf, const unsigned short* __restrict__ vbf,
                   const unsigned short* __restrict__ WpT, const unsigned short* __restrict__ WqT,
                   const unsigned short* __restrict__ WkT, const unsigned short* __restrict__ WvT,
                   const float* __restrict__ bq, const float* __restrict__ bk,
                   const float* __restrict__ bv, const float* __restrict__ U,
                   const float* __restrict__ V,
                   unsigned short* __restrict__ Rb, unsigned short* __restrict__ Qu,
                   unsigned short* __restrict__ Qv, unsigned short* __restrict__ Kb,
                   unsigned short* __restrict__ Vt){
  const int bid = blockIdx.x;
  int mode, local;
  const unsigned short *Ag, *Wt;
  if (bid < 128)      { mode = 3; local = bid;       Ag = pbf; Wt = WpT; }
  else if (bid < 384) { mode = 0; local = bid - 128; Ag = qbf; Wt = WqT; }
  else if (bid < 896) { mode = 1; local = bid - 384; Ag = kbf; Wt = WkT; }
  else                { mode = 2; local = bid - 896; Ag = vbf; Wt = WvT; }
  const int m0 = (local >> 3) * 128, n0 = (local & 7) * 128;

  const int tid = threadIdx.x;
  const int lane = tid & 63, wave = tid >> 6;
  const int lr = lane & 15, lg = lane >> 4;
  const int wm = wave >> 1, wn = wave & 1;
  __shared__ union {
    struct { unsigned short At[128 * 64]; unsigned short Bt[128 * 64]; } ab;  // 32 KB
    unsigned short tr[64 * 136];                                              // 17 KB scratch
  } smem;
  unsigned short* At = smem.ab.At;
  unsigned short* Bt = smem.ab.Bt;
  f32x4 acc[4][4] = {};

  for (int kt = 0; kt < EMB / 64; ++kt){
    const int k0 = kt * 64;
    __syncthreads();
    #pragma unroll
    for (int j = 0; j < 4; ++j){
      int row = j * 32 + (tid >> 3);
      int g = (tid & 7) ^ (row & 7);
      gload_lds16(Ag + (size_t)(m0 + row) * EMB + k0 + g * 8, &At[j * 2048 + wave * 512]);
      gload_lds16(Wt + (size_t)(n0 + row) * EMB + k0 + g * 8, &Bt[j * 2048 + wave * 512]);
    }
    __syncthreads();
    #pragma unroll
    for (int ks = 0; ks < 2; ++ks){
      bf16x8 af[4], bfr[4];
      #pragma unroll
      for (int mb = 0; mb < 4; ++mb){
        int row = wm * 64 + mb * 16 + lr;
        af[mb] = *(const bf16x8*)&At[row * 64 + ((lg + 4 * ks) ^ (row & 7)) * 8];
      }
      #pragma unroll
      for (int nb = 0; nb < 4; ++nb){
        int row = wn * 64 + nb * 16 + lr;
        bfr[nb] = *(const bf16x8*)&Bt[row * 64 + ((lg + 4 * ks) ^ (row & 7)) * 8];
      }
      __builtin_amdgcn_s_setprio(1);
      #pragma unroll
      for (int mb = 0; mb < 4; ++mb)
        #pragma unroll
        for (int nb = 0; nb < 4; ++nb)
          acc[mb][nb] = __builtin_amdgcn_mfma_f32_16x16x32_bf16(af[mb], bfr[nb], acc[mb][nb], 0, 0, 0);
      __builtin_amdgcn_s_setprio(0);
    }
  }

  if (mode == 2){
    // ---- LDS-transpose epilogue for coalesced Vt[b][h][d][kp] stores ----
    const int kp0 = m0 >> 2;
    __syncthreads();                       // At/Bt dead: all fragment reads complete
    #pragma unroll
    for (int pass = 0; pass < 2; ++pass){
      if (wn == pass){
        #pragma unroll
        for (int mb = 0; mb < 4; ++mb){
          int kp_l = wm * 16 + mb * 4 + lg;
          #pragma unroll
          for (int nb = 0; nb < 4; ++nb){
            int nl = nb * 16 + lr;         // 0..63 within this half
            float bvv = bv[n0 + pass * 64 + nl];
            #pragma unroll
            for (int i = 0; i < 4; ++i)
              smem.tr[nl * 136 + i * 32 + kp_l] = f2bf(acc[mb][nb][i] + bvv);
          }
        }
      }
      __syncthreads();
      #pragma unroll
      for (int it = 0; it < 4; ++it){
        int c = it * 256 + tid;
        int nl = c >> 4, bb = (c >> 2) & 3, kpc = c & 3;
        int n = n0 + pass * 64 + nl;
        int hh = n >> 6, dd = n & 63;
        bf16x8 vv = *(const bf16x8*)&smem.tr[nl * 136 + bb * 32 + kpc * 8];
        *(bf16x8*)&Vt[((((size_t)bb * NH + hh) * HD) + dd) * KLEN + kp0 + kpc * 8] = vv;
      }
      __syncthreads();
    }
  } else {
    #pragma unroll
    for (int mb = 0; mb < 4; ++mb){
      #pragma unroll
      for (int nb = 0; nb < 4; ++nb){
        #pragma unroll
        for (int i = 0; i < 4; ++i){
          int m = m0 + wm * 64 + mb * 16 + 4 * lg + i;
          int n = n0 + wn * 64 + nb * 16 + lr;
          float v = acc[mb][nb][i];
          if (mode == 0){
            int qq = m >> 2, b = m & 3, h = n >> 6, d = n & 63;
            size_t idx = ((((size_t)b * NH + h) * QLEN) + qq) * HD + d;
            float base = v + bq[n];
            Qu[idx] = f2bf((base + U[n]) * SLOG2E);
            Qv[idx] = f2bf((base + V[n]) * SLOG2E);
          } else if (mode == 1){
            int kp = m >> 2, b = m & 3, h = n >> 6, d = n & 63;
            Kb[((((size_t)b * NH + h) * KLEN) + kp) * HD + d] = f2bf(v + bk[n]);
          } else {
            int h = n >> 6, d = n & 63;
            Rb[((size_t)h * KLEN + m) * HD + d] = f2bf(v);
          }
        }
      }
    }
  }
}

// ---------------- output GEMM: d_out[M][1024] = alpha @ WoT^T + bo (f32 out) ----------------
__global__ __launch_bounds__(256)
void txl_gemm_out(const unsigned short* __restrict__ Ag, const unsigned short* __restrict__ Wt,
                  const float* __restrict__ bias, float* __restrict__ out0){
  const int tid = threadIdx.x;
  const int lane = tid & 63, wave = tid >> 6;
  const int lr = lane & 15, lg = lane >> 4;
  const int wm = wave >> 1, wn = wave & 1;
  const int m0 = blockIdx.y * 128, n0 = blockIdx.x * 128;
  __shared__ unsigned short At[128 * 64];
  __shared__ unsigned short Bt[128 * 64];
  f32x4 acc[4][4] = {};

  for (int kt = 0; kt < EMB / 64; ++kt){
    const int k0 = kt * 64;
    __syncthreads();
    #pragma unroll
    for (int j = 0; j < 4; ++j){
      int row = j * 32 + (tid >> 3);
      int g = (tid & 7) ^ (row & 7);
      gload_lds16(Ag + (size_t)(m0 + row) * EMB + k0 + g * 8, &At[j * 2048 + wave * 512]);
      gload_lds16(Wt + (size_t)(n0 + row) * EMB + k0 + g * 8, &Bt[j * 2048 + wave * 512]);
    }
    __syncthreads();
    #pragma unroll
    for (int ks = 0; ks < 2; ++ks){
      bf16x8 af[4], bfr[4];
      #pragma unroll
      for (int mb = 0; mb < 4; ++mb){
        int row = wm * 64 + mb * 16 + lr;
        af[mb] = *(const bf16x8*)&At[row * 64 + ((lg + 4 * ks) ^ (row & 7)) * 8];
      }
      #pragma unroll
      for (int nb = 0; nb < 4; ++nb){
        int row = wn * 64 + nb * 16 + lr;
        bfr[nb] = *(const bf16x8*)&Bt[row * 64 + ((lg + 4 * ks) ^ (row & 7)) * 8];
      }
      __builtin_amdgcn_s_setprio(1);
      #pragma unroll
      for (int mb = 0; mb < 4; ++mb)
        #pragma unroll
        for (int nb = 0; nb < 4; ++nb)
          acc[mb][nb] = __builtin_amdgcn_mfma_f32_16x16x32_bf16(af[mb], bfr[nb], acc[mb][nb], 0, 0, 0);
      __builtin_amdgcn_s_setprio(0);
    }
  }
  #pragma unroll
  for (int mb = 0; mb < 4; ++mb)
    #pragma unroll
    for (int nb = 0; nb < 4; ++nb)
      #pragma unroll
      for (int i = 0; i < 4; ++i){
        int m = m0 + wm * 64 + mb * 16 + 4 * lg + i;
        int n = n0 + wn * 64 + nb * 16 + lr;
        out0[(size_t)m * EMB + n] = acc[mb][nb][i] + bias[n];
      }
}

// ---------------- fused attention: R15 body + XCD-aware block swizzle ----------------
// 1-D grid of 1024 blocks. wg = (bid%8)*128 + bid/8 (bijective): each XCD receives
// contiguous wg runs = whole (h,b) groups, so its L2 holds that group's K/V/R
// (~1.2 MB x ~2 live < 4 MB). Longest-qt-first preserved within each group.
__global__ __launch_bounds__(256)
void txl_attn(const unsigned short* __restrict__ Qu, const unsigned short* __restrict__ Qv,
              const unsigned short* __restrict__ Kb, const unsigned short* __restrict__ Vt,
              const unsigned short* __restrict__ Rb, unsigned short* __restrict__ alpha){
  const int tid = threadIdx.x, lane = tid & 63, wave = tid >> 6;
  const int lr = lane & 15, lg = lane >> 4;
  const int wg = (blockIdx.x & 7) * 128 + (blockIdx.x >> 3);   // XCD-contiguous (h,b) groups
  const int qt = 15 - (wg & 15);               // longest blocks first within each group
  const int hb = wg >> 4;
  const int h = hb & 15, b = hb >> 4;
  const int q0 = qt * 64;
  const int myq0 = q0 + 16 * wave;

  __shared__ union { unsigned short q[2][64 * 64]; unsigned short p[4][16 * 64]; } smq; // 16 KB
  __shared__ unsigned short sm_k[64 * 64];      // 8 KB
  __shared__ unsigned short sm_v[64 * 64];      // 8 KB
  __shared__ unsigned short sm_r[128 * 64];     // 16 KB ring
  __shared__ float sm_t[4][16 * 81];            // 20.25 KB

  const unsigned short* quB = Qu + (((size_t)b * NH + h) * QLEN) * HD;
  const unsigned short* qvB = Qv + (((size_t)b * NH + h) * QLEN) * HD;
  const unsigned short* kB  = Kb + (((size_t)b * NH + h) * KLEN) * HD;
  const unsigned short* vB  = Vt + (((size_t)b * NH + h) * HD) * KLEN;
  const unsigned short* rB  = Rb + ((size_t)h * KLEN) * HD;

  // stage Qu/Qv tiles + full first R band [rbase0, rbase0+128)
  #pragma unroll
  for (int j = 0; j < 2; ++j){
    int row = j * 32 + (tid >> 3);
    int g = (tid & 7) ^ (row & 7);
    gload_lds16(quB + (size_t)(q0 + row) * HD + g * 8, &smq.q[0][j * 2048 + wave * 512]);
    gload_lds16(qvB + (size_t)(q0 + row) * HD + g * 8, &smq.q[1][j * 2048 + wave * 512]);
  }
  const int rbase0 = (QLEN - 64) - q0;         // kt=0 band origin (multiple of 64, <= 960)
  #pragma unroll
  for (int j = 0; j < 4; ++j){
    int S = rbase0 + j * 32;                   // block start; S&7 == 0
    int rs = S + (tid >> 3);                   // < 1088, no clamp needed
    int g = (tid & 7) ^ (rs & 7);
    gload_lds16(rB + (size_t)rs * HD + g * 8, &sm_r[(S & 127) * 64 + wave * 512]);
  }
  __syncthreads();
  bf16x8 qfu[2], qfv[2];
  {
    int row = 16 * wave + lr;
    #pragma unroll
    for (int ks = 0; ks < 2; ++ks){
      qfu[ks] = *(const bf16x8*)&smq.q[0][row * 64 + ((lg + 4 * ks) ^ (row & 7)) * 8];
      qfv[ks] = *(const bf16x8*)&smq.q[1][row * 64 + ((lg + 4 * ks) ^ (row & 7)) * 8];
    }
  }

  f32x4 o[4] = {};
  float ls[4] = {0.f, 0.f, 0.f, 0.f};

  const int nk = qt + 17;                      // qt <= 15 -> nk <= 32 always
  const int roff = 48 - 16 * wave;             // this wave's R rows within the 128-row band

  for (int kt = 0; kt < nk; ++kt){
    const int k0 = kt * 64;
    const int rbase = k0 + (QLEN - 64) - q0;   // band origin (>= 0, multiple of 64)
    const int roff64 = rbase & 64;             // ring rotation for this tile
    __syncthreads();
    // stage K, V tiles
    #pragma unroll
    for (int j = 0; j < 2; ++j){
      int row = j * 32 + (tid >> 3);
      int g = (tid & 7) ^ (row & 7);
      gload_lds16(kB + (size_t)(k0 + row) * HD + g * 8, &sm_k[j * 2048 + wave * 512]);
      gload_lds16(vB + (size_t)row * KLEN + k0 + g * 8, &sm_v[j * 2048 + wave * 512]);
    }
    // ring: stage only the 64 NEW band rows [rbase+64, rbase+128) (kt>0);
    // their slots held rows expired two tiles ago — loop-top barrier protects them.
    if (kt > 0){
      #pragma unroll
      for (int j = 0; j < 2; ++j){
        int S = rbase + 64 + j * 32;           // block start; S&7 == 0
        int rs = S + (tid >> 3);
        int rc = rs < KLEN - 1 ? rs : KLEN - 1;
        int g = (tid & 7) ^ (rs & 7);
        gload_lds16(rB + (size_t)rc * HD + g * 8, &sm_r[(S & 127) * 64 + wave * 512]);
      }
    }
    __syncthreads();

    // content scores S_c[16q][64k] and position band T[16q][80r]
    f32x4 sc[4] = {};
    f32x4 tt[5] = {};
    __builtin_amdgcn_s_setprio(1);
    #pragma unroll
    for (int ks = 0; ks < 2; ++ks){
      #pragma unroll
      for (int nb = 0; nb < 4; ++nb){
        int row = nb * 16 + lr;
        bf16x8 kf = *(const bf16x8*)&sm_k[row * 64 + ((lg + 4 * ks) ^ (row & 7)) * 8];
        sc[nb] = __builtin_amdgcn_mfma_f32_16x16x32_bf16(qfu[ks], kf, sc[nb], 0, 0, 0);
      }
      #pragma unroll
      for (int rb = 0; rb < 5; ++rb){
        int row = roff + rb * 16 + lr;
        int slot = row ^ roff64;               // ring-rotated slot; slot&7 == row&7
        bf16x8 rf = *(const bf16x8*)&sm_r[slot * 64 + ((lg + 4 * ks) ^ (row & 7)) * 8];
        tt[rb] = __builtin_amdgcn_mfma_f32_16x16x32_bf16(qfv[ks], rf, tt[rb], 0, 0, 0);
      }
    }
    __builtin_amdgcn_s_setprio(0);

    // sm_t round-trip for the rel-shift diagonal (per-wave region; stride 81)
    float* tw = sm_t[wave];
    #pragma unroll
    for (int rb = 0; rb < 5; ++rb)
      #pragma unroll
      for (int i = 0; i < 4; ++i)
        tw[(4 * lg + i) * 81 + rb * 16 + lr] = tt[rb][i];
    asm volatile("s_waitcnt lgkmcnt(0)" ::: "memory");

    // assemble scores, exp2 (fixed-max), deferred row-sum, write P.
    // Mask applies ONLY in the final tile (k0+63 > q0+1024 iff kt == nk-1).
    if (kt + 1 < nk){
      #pragma unroll
      for (int i = 0; i < 4; ++i){
        int qq = 4 * lg + i;
        float rs = 0.f;
        #pragma unroll
        for (int nb = 0; nb < 4; ++nb){
          int kk = nb * 16 + lr;
          float p = exp2f(sc[nb][i] + tw[qq * 81 + kk + 15 - qq]);
          rs += p;
          smq.p[wave][qq * 64 + (((kk >> 3) ^ (qq & 7)) << 3) + (kk & 7)] = f2bf(p);
        }
        ls[i] += rs;
      }
    } else {
      #pragma unroll
      for (int i = 0; i < 4; ++i){
        int qq = 4 * lg + i;
        int qglob = myq0 + qq;
        float rs = 0.f;
        #pragma unroll
        for (int nb = 0; nb < 4; ++nb){
          int kk = nb * 16 + lr;
          float s = sc[nb][i] + tw[qq * 81 + kk + 15 - qq];
          if (k0 + kk > qglob + PREVL) s = -1e30f;
          float p = exp2f(s);
          rs += p;
          smq.p[wave][qq * 64 + (((kk >> 3) ^ (qq & 7)) << 3) + (kk & 7)] = f2bf(p);
        }
        ls[i] += rs;
      }
    }
    asm volatile("s_waitcnt lgkmcnt(0)" ::: "memory");

    // PV: O[16q][64d] += P @ V
    __builtin_amdgcn_s_setprio(1);
    #pragma unroll
    for (int ks = 0; ks < 2; ++ks){
      bf16x8 pa = *(const bf16x8*)&smq.p[wave][lr * 64 + ((lg + 4 * ks) ^ (lr & 7)) * 8];
      #pragma unroll
      for (int db = 0; db < 4; ++db){
        int row = db * 16 + lr;
        bf16x8 vf = *(const bf16x8*)&sm_v[row * 64 + ((lg + 4 * ks) ^ (row & 7)) * 8];
        o[db] = __builtin_amdgcn_mfma_f32_16x16x32_bf16(pa, vf, o[db], 0, 0, 0);
      }
    }
    __builtin_amdgcn_s_setprio(0);
  }

  // epilogue: reduce deferred row-sums, normalize, write alpha[q][b][h*64+d]
  #pragma unroll
  for (int i = 0; i < 4; ++i){
    float s = ls[i];
    s += __shfl_xor(s, 1); s += __shfl_xor(s, 2);
    s += __shfl_xor(s, 4); s += __shfl_xor(s, 8);
    float inv = 1.0f / s;
    int q = myq0 + 4 * lg + i;
    #pragma unroll
    for (int db = 0; db < 4; ++db){
      int e = (h << 6) + db * 16 + lr;
      alpha[((size_t)q * BSZ + b) * EMB + e] = f2bf(o[db][i] * inv);
    }
  }
}

extern "C" void kernel_launch(void* const* d_in, const int* in_sizes, int n_in,
                              void* d_out, int out_size, void* d_ws, size_t ws_size,
                              hipStream_t stream) {
  const float* query = (const float*)d_in[0];
  const float* key   = (const float*)d_in[1];
  const float* value = (const float*)d_in[2];
  const float* pos   = (const float*)d_in[3];
  const float* U     = (const float*)d_in[4];
  const float* V     = (const float*)d_in[5];
  const float* Wq    = (const float*)d_in[6];
  const float* bq    = (const float*)d_in[7];
  const float* Wk    = (const float*)d_in[8];
  const float* bk    = (const float*)d_in[9];
  const float* Wv    = (const float*)d_in[10];
  const float* bv    = (const float*)d_in[11];
  const float* Wp    = (const float*)d_in[12];
  const float* Wo    = (const float*)d_in[13];
  const float* bo    = (const float*)d_in[14];

  char* w = (char*)d_ws;
  const size_t MB = 1u << 20;
  unsigned short* WqT = (unsigned short*)(w + 0 * MB);
  unsigned short* WkT = (unsigned short*)(w + 2 * MB);
  unsigned short* WvT = (unsigned short*)(w + 4 * MB);
  unsigned short* WpT = (unsigned short*)(w + 6 * MB);
  unsigned short* WoT = (unsigned short*)(w + 8 * MB);
  unsigned short* Qu  = (unsigned short*)(w + 10 * MB);
  unsigned short* Qv  = (unsigned short*)(w + 18 * MB);
  unsigned short* Kb  = (unsigned short*)(w + 26 * MB);
  unsigned short* Vt  = (unsigned short*)(w + 42 * MB);
  unsigned short* Rb  = (unsigned short*)(w + 58 * MB);
  unsigned short* qbf = (unsigned short*)(w + 62 * MB);   // dead after proj-GEMM -> alpha
  unsigned short* kbf = (unsigned short*)(w + 70 * MB);
  unsigned short* vbf = (unsigned short*)(w + 86 * MB);
  unsigned short* pbf = (unsigned short*)(w + 102 * MB);
  unsigned short* alpha = qbf;

  txl_prep<<<dim3(7168), 256, 0, stream>>>(Wq, Wk, Wv, Wp, Wo, WqT, WkT, WvT, WpT, WoT,
                                           query, key, value, pos, qbf, kbf, vbf, pbf);

  txl_gemm_proj<<<dim3(1408), 256, 0, stream>>>(pbf, qbf, kbf, vbf, WpT, WqT, WkT, WvT,
                                                bq, bk, bv, U, V, Rb, Qu, Qv, Kb, Vt);

  txl_attn<<<dim3(1024), 256, 0, stream>>>(Qu, Qv, Kb, Vt, Rb, alpha);

  txl_gemm_out<<<dim3(8, 32), 256, 0, stream>>>(alpha, WoT, bo, (float*)d_out);
}